// Round 7
// baseline (939.002 us; speedup 1.0000x reference)
//
#include <hip/hip_runtime.h>
#include <hip/hip_bf16.h>
#include <math.h>

// QuantumLLM fused pipeline, round 7: round-6's race-safe stage rotation + inline-asm
// ds_read_b128 (single-variable change). Plain C++ LDS reads alias the global_load_lds
// destination array, so hipcc inserts its own vmcnt(0) drains before every phase's
// reads -- that is why rounds 3/4/6's wait-schedule edits were all no-ops (MfmaUtil
// pinned at 28%). Asm reads hide the alias; correctness is carried by the round-6
// ledger (each stage lands after its region's reads retired, vmcnt(6) gives every
// load >=3 phases of flight) + lgkmcnt(0)+sched_barrier(0) before MFMA (rule #18).
// Algebra (rounds 1-4): qkv fold K3072->1024, 4/6 blocks; coll==1 const excitation;
// op_w folded into V so PV writes d_out directly; PV split-K z=4 + combine.

#define TWO_PI_F 6.283185307179586f

typedef __attribute__((ext_vector_type(4))) float f32x4;
typedef __attribute__((ext_vector_type(8))) short bf16x8;
typedef __attribute__((ext_vector_type(4))) unsigned short u16x4;
typedef __hip_bfloat16 bf16;

__device__ __forceinline__ void gl_lds16(const void* g, void* l) {
  __builtin_amdgcn_global_load_lds((const __attribute__((address_space(1))) void*)g,
                                   (__attribute__((address_space(3))) void*)l, 16, 0, 0);
}
__device__ __forceinline__ unsigned lds_off(const void* p) {
  return (unsigned)(unsigned long long)(const __attribute__((address_space(3))) void*)p;
}
__device__ __forceinline__ f32x4 ds_read128(unsigned addr) {
  f32x4 r;
  asm volatile("ds_read_b128 %0, %1" : "=v"(r) : "v"(addr));
  return r;
}
__device__ __forceinline__ unsigned short f2bf_bits(float f) {
  union { __hip_bfloat16 h; unsigned short u; } cv;
  cv.h = __float2bfloat16(f);
  return cv.u;
}
__device__ __forceinline__ float bf_bits2f(unsigned short b) {
  union { unsigned int u; float f; } cv;
  cv.u = ((unsigned int)b) << 16;
  return cv.f;
}

#define BAR8()                          \
  asm volatile("" ::: "memory");        \
  __builtin_amdgcn_s_barrier();         \
  asm volatile("" ::: "memory")
#define WAITV6() asm volatile("s_waitcnt vmcnt(6)" ::: "memory")
// after barrier #1 of a ds-reading phase: wait own ds_reads, pin schedule (rule #18)
#define LGKM0()                                        \
  asm volatile("s_waitcnt lgkmcnt(0)" ::: "memory");   \
  __builtin_amdgcn_sched_barrier(0)

// ============ 8-phase 256x256 GEMM: C = epi(A * B^T * scale + bias) ============
// BM=BN=256, BK=64, 512 thr, 8 waves (2M x 4N), per-wave 128x64 out. LDS 128 KiB
// double-buffered, XOR-swizzled (16B slot ^= row&7) both-sides.
// Stage rotation (race-safe, proven round 6):
//   P1: B(k1)h1->buf1 | P3: A(k2)h0->buf0 | P4: A(k2)h1,B(k2)h0->buf0
//   P5: B(k2)h1->buf0 | P7: A(k3)h0->buf1 | P8: A(k3)h1,B(k3)h0->buf1
// Waits: vmcnt(6) at P4/P8-end retires the 8 loads of the buffer about to be read;
// youngest retired load is 3 phases old.
// ORD=1: mfma(b,a) -> lane = C-row, regs = 4 consecutive C-cols (packed stores).
// ORD=0: mfma(a,b) -> regs = 4 consecutive C-rows (for v2T transposed store).
// EPI: 0 bias+bf16; 1 bias+gelu+bf16; 2 scale+bf16 (z batch); 3 PV split-K
//      (z=kchunk*2+batch; chunk0 +bias split fp32 out, chunk1 fp32 partial);
//      4 qkv (col<1024 -> qk, else v2T transposed packed).
template <int EPI, int ORD>
__global__ __launch_bounds__(512, 2) void gemm8p(
    const bf16* __restrict__ A, const bf16* __restrict__ B, void* __restrict__ C,
    void* __restrict__ Cx, const float* __restrict__ bias, int K, int lda, int ldb, int ldc,
    float scale, long long zsa, long long zsb, long long zsc, float* __restrict__ P0,
    float* __restrict__ P1) {
  __shared__ __align__(16) char lds[131072];
  const int tid = threadIdx.x;
  const int lane = tid & 63, wid = tid >> 6;
  const int wm = wid >> 2, wn = wid & 3;

  // XCD-bijective block swizzle (m204)
  const int gx = gridDim.x, gy = gridDim.y, gz = gridDim.z;
  int flat = blockIdx.x + gx * (blockIdx.y + gy * blockIdx.z);
  {
    const int nwg = gx * gy * gz;
    const int q = nwg >> 3, r = nwg & 7;
    const int x = flat & 7, loc = flat >> 3;
    flat = (x < r ? x * (q + 1) : r * (q + 1) + (x - r) * q) + loc;
  }
  const int bx = flat % gx;
  const int by = (flat / gx) % gy;
  const int bz = flat / (gx * gy);
  const int bm = by * 256, bn = bx * 256;

  const bf16 *Az, *Bz;
  if constexpr (EPI == 3) {
    const int b = bz & 1, c = bz >> 1;
    Az = A + (long long)b * zsa + c * 2048;
    Bz = B + (long long)b * zsb + c * 2048;
  } else {
    Az = A + (long long)bz * zsa;
    Bz = B + (long long)bz * zsb;
  }

  f32x4 acc[8][4];
#pragma unroll
  for (int i = 0; i < 8; ++i)
#pragma unroll
    for (int j = 0; j < 4; ++j) acc[i][j] = (f32x4){0.f, 0.f, 0.f, 0.f};

  f32x4 afr[8][2];  // asm ds_read results, bit-cast to bf16x8 at MFMA
  f32x4 bfr[2][2];

  // staging constants (write side of the involution)
  const int srow = wid * 16 + (lane >> 3);
  const int sslot = (lane & 7) ^ (lane >> 3);
  const int sldsb = wid * 2048 + lane * 16;

  auto STG = [&](int isA, int buf, int h, int kt) {
#pragma unroll
    for (int l = 0; l < 2; ++l) {
      const int row = h * 128 + srow + l * 8;
      const bf16* src = isA ? Az : Bz;
      const int ld = isA ? lda : ldb;
      const int r0 = isA ? bm : bn;
      const long long g = (long long)(r0 + row) * ld + (long long)kt * 64 + sslot * 8;
      gl_lds16(src + g, &lds[buf * 65536 + (isA ? 0 : 32768) + h * 16384 + sldsb + l * 1024]);
    }
  };

  // ds-read constants (read side, same involution), raw LDS byte addresses
  const unsigned ldsb0 = lds_off(&lds[0]);
  const int swzr = (lane & 7) << 4;
  const int kbs = (lane >> 4) << 4;
  const unsigned cby0 = (unsigned)((0 + kbs) ^ swzr);
  const unsigned cby1 = (unsigned)((64 + kbs) ^ swzr);
  const unsigned aBase = ldsb0 + (unsigned)((wm * 128 + (lane & 15)) * 128);
  const unsigned bBase = ldsb0 + 32768u + (unsigned)((wn * 64 + (lane & 15)) * 128);

  auto LDA4 = [&](int buf, int i0) {
    const unsigned base = aBase + (unsigned)buf * 65536u;
#pragma unroll
    for (int t = 0; t < 4; ++t) {
      afr[i0 + t][0] = ds_read128(base + (unsigned)(i0 + t) * 2048u + cby0);
      afr[i0 + t][1] = ds_read128(base + (unsigned)(i0 + t) * 2048u + cby1);
    }
  };
  auto LDB2 = [&](int buf, int j0) {
    const unsigned base = bBase + (unsigned)buf * 65536u;
#pragma unroll
    for (int t = 0; t < 2; ++t) {
      bfr[t][0] = ds_read128(base + (unsigned)(j0 + t) * 2048u + cby0);
      bfr[t][1] = ds_read128(base + (unsigned)(j0 + t) * 2048u + cby1);
    }
  };
  auto MFMA16 = [&](int i0, int j0) {
    __builtin_amdgcn_s_setprio(1);
#pragma unroll
    for (int t = 0; t < 4; ++t)
#pragma unroll
      for (int u = 0; u < 2; ++u)
#pragma unroll
        for (int kk = 0; kk < 2; ++kk) {
          const bf16x8 av = __builtin_bit_cast(bf16x8, afr[i0 + t][kk]);
          const bf16x8 bv = __builtin_bit_cast(bf16x8, bfr[u][kk]);
          if constexpr (ORD == 0)
            acc[i0 + t][j0 + u] = __builtin_amdgcn_mfma_f32_16x16x32_bf16(
                av, bv, acc[i0 + t][j0 + u], 0, 0, 0);
          else
            acc[i0 + t][j0 + u] = __builtin_amdgcn_mfma_f32_16x16x32_bf16(
                bv, av, acc[i0 + t][j0 + u], 0, 0, 0);
        }
    __builtin_amdgcn_s_setprio(0);
  };

  const int nkt = K >> 6;
  const int nit = nkt >> 1;

  // prologue: buf0 full (k0), buf1 A(k1) + B(k1)h0 => 14 loads; retire buf0's 8.
  STG(1, 0, 0, 0);
  STG(1, 0, 1, 0);
  STG(0, 0, 0, 0);
  STG(0, 0, 1, 0);
  STG(1, 1, 0, 1);
  STG(1, 1, 1, 1);
  STG(0, 1, 0, 1);
  WAITV6();
  BAR8();

  for (int i = 0; i < nit; ++i) {
    const int k1 = 2 * i + 1;
    const int k2t = 2 * i + 2, k3t = 2 * i + 3;
    const int k2 = (k2t < nkt) ? k2t : 0;
    const int k3 = (k3t < nkt) ? k3t : 0;
    // P1: read buf0 A[0-3],B[0-1]; stage B(k1)h1 -> buf1 (buf1 B free since prev-P7)
    LDA4(0, 0);
    LDB2(0, 0);
    STG(0, 1, 1, k1);
    BAR8();
    LGKM0();
    MFMA16(0, 0);
    BAR8();
    // P2: read buf0 A[4-7]
    LDA4(0, 4);
    BAR8();
    LGKM0();
    MFMA16(4, 0);
    BAR8();
    // P3: read buf0 B[2-3]; stage A(k2)h0 -> buf0 (buf0 A reads done at P2-end)
    LDB2(0, 2);
    STG(1, 0, 0, k2);
    BAR8();
    LGKM0();
    MFMA16(0, 2);
    BAR8();
    // P4: stage A(k2)h1, B(k2)h0 -> buf0 (buf0 B reads done at P3-end);
    //     vmcnt(6) retires all of buf1's {A(k1),B(k1)} (leads 5/4/4/3 phases)
    STG(1, 0, 1, k2);
    STG(0, 0, 0, k2);
    BAR8();
    MFMA16(4, 2);
    WAITV6();
    BAR8();
    // P5: read buf1 A[0-3],B[0-1]; stage B(k2)h1 -> buf0
    LDA4(1, 0);
    LDB2(1, 0);
    STG(0, 0, 1, k2);
    BAR8();
    LGKM0();
    MFMA16(0, 0);
    BAR8();
    // P6: read buf1 A[4-7]
    LDA4(1, 4);
    BAR8();
    LGKM0();
    MFMA16(4, 0);
    BAR8();
    // P7: read buf1 B[2-3]; stage A(k3)h0 -> buf1 (buf1 A reads done at P6-end)
    LDB2(1, 2);
    STG(1, 1, 0, k3);
    BAR8();
    LGKM0();
    MFMA16(0, 2);
    BAR8();
    // P8: stage A(k3)h1, B(k3)h0 -> buf1 (buf1 B reads done at P7-end);
    //     vmcnt(6) retires all of buf0's {A(k2),B(k2)}
    STG(1, 1, 1, k3);
    STG(0, 1, 0, k3);
    BAR8();
    MFMA16(4, 2);
    WAITV6();
    BAR8();
  }

  // ---- epilogue ----
  const int fr = lane & 15, ksl = lane >> 4;
#pragma unroll
  for (int i = 0; i < 8; ++i)
#pragma unroll
    for (int j = 0; j < 4; ++j) {
      if constexpr (ORD == 1) {
        // lane fr = row, regs = 4 consecutive cols
        const int row = bm + wm * 128 + i * 16 + fr;
        const int col0 = bn + wn * 64 + j * 16 + ksl * 4;
        f32x4 v = acc[i][j];
#pragma unroll
        for (int r = 0; r < 4; ++r) v[r] *= scale;
        if constexpr (EPI == 0 || EPI == 1) {
          if (bias) {
            const f32x4 bv = *(const f32x4*)&bias[col0];
            v += bv;
          }
        }
        if constexpr (EPI == 1) {
#pragma unroll
          for (int r = 0; r < 4; ++r) {
            const float t = v[r];
            float y = 0.7978845608028654f * (t + 0.044715f * t * t * t);
            y = fminf(fmaxf(y, -15.f), 15.f);
            const float e = __expf(2.f * y);
            v[r] = t * e / (1.f + e);
          }
        }
        if constexpr (EPI == 3) {
          const int b = bz & 1, c = bz >> 1;
          if (c == 0) {
            const f32x4 bv = *(const f32x4*)&bias[col0];
            v += bv;
            float* dst = (col0 < 512) ? (float*)C : (float*)Cx;
            const long long rbase = zsc + (long long)b * 4096 + row;
            *(f32x4*)&dst[rbase * 512 + (col0 & 511)] = v;
          } else {
            float* dst = b ? P1 : P0;
            *(f32x4*)&dst[(long long)row * 1024 + col0] = v;
          }
        } else {
          bf16* cc = (bf16*)C;
          if constexpr (EPI == 2) cc += (long long)bz * zsc;
          u16x4 w;
#pragma unroll
          for (int r = 0; r < 4; ++r) w[r] = f2bf_bits(v[r]);
          *(u16x4*)&cc[(long long)row * ldc + col0] = w;
        }
      } else {
        // ORD==0 (EPI 4): regs = 4 consecutive rows, lane fr = col
        const int row0 = bm + wm * 128 + i * 16 + ksl * 4;
        const int col = bn + wn * 64 + j * 16 + fr;
        float v[4];
#pragma unroll
        for (int r = 0; r < 4; ++r) {
          v[r] = acc[i][j][r] * scale;
          if (bias) v[r] += bias[col];
        }
        if (col < 1024) {
          bf16* cc = (bf16*)C;
#pragma unroll
          for (int r = 0; r < 4; ++r)
            cc[(long long)(row0 + r) * 1024 + col] = __float2bfloat16(v[r]);
        } else {
          const int d = col - 1024, b = row0 >> 12, mm = row0 & 4095;
          u16x4 w;
#pragma unroll
          for (int r = 0; r < 4; ++r) w[r] = f2bf_bits(v[r]);
          *(u16x4*)((unsigned short*)Cx + ((long long)(b * 1024 + d)) * 4096 + mm) = w;
        }
      }
    }
}

// ---------------- combine: out += partial (one batch-pair) ----------------
__global__ __launch_bounds__(256) void combine_kernel(const float* __restrict__ p0,
                                                      const float* __restrict__ p1,
                                                      float* __restrict__ out0,
                                                      float* __restrict__ out1) {
  const int idx = blockIdx.x * 256 + threadIdx.x;
  const int b = idx >> 20;
  const int rem = idx & 1048575;
  const int row = rem >> 8;
  const int c4 = rem & 255;
  const float* p = b ? p1 : p0;
  const f32x4 v = *(const f32x4*)(p + (long long)row * 1024 + c4 * 4);
  float* dst = (c4 < 128) ? out0 : out1;
  const long long o = ((long long)(b * 4096 + row)) * 512 + (c4 & 127) * 4;
  f32x4 d = *(f32x4*)(dst + o);
  d += v;
  *(f32x4*)(dst + o) = d;
}

// ---------------- LayerNorm + phase ops ----------------
__global__ __launch_bounds__(256) void ln_phase_kernel(
    const bf16* __restrict__ g, bf16* __restrict__ u, const float* __restrict__ ln_g,
    const float* __restrict__ ln_b, const float* __restrict__ lcos,
    const float* __restrict__ lsin, const float* __restrict__ cost,
    const float* __restrict__ sint) {
  __shared__ float sg[1024];
  __shared__ float red[4];
  const int tid = threadIdx.x;
  const int lane = tid & 63, wid = tid >> 6;
  const long long row = blockIdx.x;
  const bf16* gr = g + row * 1024;

  const u16x4 raw = *(const u16x4*)(gr + tid * 4);
  float lv[4];
  float lsum = 0.f;
#pragma unroll
  for (int e = 0; e < 4; ++e) {
    lv[e] = bf_bits2f(raw[e]);
    lsum += lv[e];
  }
  *(f32x4*)&sg[tid * 4] = *(f32x4*)lv;
#pragma unroll
  for (int off = 32; off > 0; off >>= 1) lsum += __shfl_xor(lsum, off);
  if (lane == 0) red[wid] = lsum;
  __syncthreads();
  const float mu = (red[0] + red[1] + red[2] + red[3]) * (1.0f / 1024.0f);
  __syncthreads();
  float lvar = 0.f;
#pragma unroll
  for (int e = 0; e < 4; ++e) {
    const float d = lv[e] - mu;
    lvar += d * d;
  }
#pragma unroll
  for (int off = 32; off > 0; off >>= 1) lvar += __shfl_xor(lvar, off);
  if (lane == 0) red[wid] = lvar;
  __syncthreads();
  const float var = (red[0] + red[1] + red[2] + red[3]) * (1.0f / 1024.0f);
  const float rs = rsqrtf(var + 1e-5f);

#pragma unroll
  for (int kk = 0; kk < 2; ++kk) {
    const int p = tid + kk * 256;
    const float rp = (sg[p] - mu) * rs * ln_g[p] + ln_b[p];
    const float ip = (sg[p + 512] - mu) * rs * ln_g[p + 512] + ln_b[p + 512];
    const float ang = atan2f(ip + 1e-8f, rp + 1e-8f);
    int idx = (int)((ang / TWO_PI_F) * 1023.0f);
    idx = idx < 0 ? idx + 1024 : idx;
    float real = rp * cost[idx];
    float imag = ip * sint[idx];
    const float nrm = rsqrtf(real * real + imag * imag + 1e-8f) * 0.044194173824159216f;
    real *= nrm;
    imag *= nrm;
    const float amp = sqrtf(real * real + imag * imag + 1e-8f);
    const float coll = (amp < 0.1f) ? 1.0f : 0.0f;
    real += coll * lcos[p];
    imag += coll * lsin[p];
    const float n2 = rsqrtf(real * real + imag * imag + 1e-8f);
    u[row * 1024 + p] = __float2bfloat16(real * n2);
    u[row * 1024 + 512 + p] = __float2bfloat16(imag * n2);
  }
}

// ---------------- rowwise softmax in place on bf16 scores ----------------
__global__ __launch_bounds__(256) void softmax_kernel(bf16* __restrict__ s) {
  __shared__ float ss[4096];
  __shared__ float red[4];
  const int tid = threadIdx.x;
  const int lane = tid & 63, wid = tid >> 6;
  bf16* sr = s + (long long)blockIdx.x * 4096;
  float mx = -3.0e38f;
#pragma unroll
  for (int k = 0; k < 4; ++k) {
    const int base = (k * 256 + tid) * 4;
    const u16x4 raw = *(const u16x4*)(sr + base);
    f32x4 f;
#pragma unroll
    for (int e = 0; e < 4; ++e) {
      f[e] = bf_bits2f(raw[e]);
      mx = fmaxf(mx, f[e]);
    }
    *(f32x4*)&ss[base] = f;
  }
#pragma unroll
  for (int off = 32; off > 0; off >>= 1) mx = fmaxf(mx, __shfl_xor(mx, off));
  if (lane == 0) red[wid] = mx;
  __syncthreads();
  mx = fmaxf(fmaxf(red[0], red[1]), fmaxf(red[2], red[3]));
  __syncthreads();
  float sum = 0.f;
#pragma unroll
  for (int k = 0; k < 4; ++k) {
    const int base = (k * 256 + tid) * 4;
    f32x4 f = *(f32x4*)&ss[base];
#pragma unroll
    for (int e = 0; e < 4; ++e) {
      f[e] = __expf(f[e] - mx);
      sum += f[e];
    }
    *(f32x4*)&ss[base] = f;
  }
#pragma unroll
  for (int off = 32; off > 0; off >>= 1) sum += __shfl_xor(sum, off);
  if (lane == 0) red[wid] = sum;
  __syncthreads();
  const float inv = 1.0f / (red[0] + red[1] + red[2] + red[3]);
#pragma unroll
  for (int k = 0; k < 4; ++k) {
    const int base = (k * 256 + tid) * 4;
    const f32x4 f = *(f32x4*)&ss[base];
    u16x4 w;
#pragma unroll
    for (int e = 0; e < 4; ++e) w[e] = f2bf_bits(f[e] * inv);
    *(u16x4*)(sr + base) = w;
  }
}

// ---------------- prep ----------------
__global__ void cast4_f2b(const float* __restrict__ in, bf16* __restrict__ out, long long n4) {
  long long i = (long long)blockIdx.x * blockDim.x + threadIdx.x;
  const long long stride = (long long)gridDim.x * blockDim.x;
  for (; i < n4; i += stride) {
    const f32x4 f = *(const f32x4*)(in + i * 4);
    u16x4 w;
#pragma unroll
    for (int e = 0; e < 4; ++e) w[e] = f2bf_bits(f[e]);
    *(u16x4*)((unsigned short*)out + i * 4) = w;
  }
}

__global__ void fold_qkv(const float* __restrict__ w, const float* __restrict__ b,
                         bf16* __restrict__ weff, bf16* __restrict__ wvT,
                         float* __restrict__ beff) {
  const int i = blockIdx.x * blockDim.x + threadIdx.x;
  if (i < 2048 * 1024) {
    const int o = i >> 10, j = i & 1023;
    if (o < 1024) {
      const int so = (o < 512) ? o : o + 512;
      const float* wr = w + (long long)so * 3072;
      weff[i] = __float2bfloat16(wr[j] + wr[1024 + j] + wr[2048 + j]);
      if (j == 0) beff[o] = b[so];
    } else {
      const int t = o - 1024;
      const float* wr = w + (long long)(2048 + t) * 3072;
      wvT[(long long)j * 1024 + t] = __float2bfloat16(wr[j] + wr[1024 + j] + wr[2048 + j]);
    }
  }
}

__global__ void bias_fold(const float* __restrict__ op_w, const float* __restrict__ qkv_b,
                          float* __restrict__ beff) {
  const int o = blockIdx.x * blockDim.x + threadIdx.x;
  if (o < 1024) {
    const float* wr = op_w + (long long)o * 1024;
    float s = 0.f;
    for (int t = 0; t < 1024; ++t) s += wr[t] * qkv_b[2048 + t];
    beff[1024 + o] = s;
  }
}

__global__ void tables_kernel(float* __restrict__ cost, float* __restrict__ sint,
                              float* __restrict__ lcos, float* __restrict__ lsin,
                              const float* __restrict__ exc) {
  const int i = blockIdx.x * blockDim.x + threadIdx.x;
  const double step = 6.283185307179586 / 1023.0;
  if (i < 1024) {
    const float a = (float)((double)i * step);
    cost[i] = cosf(a);
    sint[i] = sinf(a);
  }
  if (i < 512) {
    const float el = ((float)i / 511.0f) * TWO_PI_F;
    const float m = fmodf(el, TWO_PI_F);
    int li = (int)((m / TWO_PI_F) * 1024.0f);
    li = min(max(li, 0), 1023);
    const float a = (float)((double)li * step);
    lcos[i] = cosf(a) * exc[0];
    lsin[i] = sinf(a) * exc[0];
  }
}

extern "C" void kernel_launch(void* const* d_in, const int* in_sizes, int n_in, void* d_out,
                              int out_size, void* d_ws, size_t ws_size, hipStream_t stream) {
  const float* x = (const float*)d_in[0];
  const float* ft_w = (const float*)d_in[1];
  const float* ft_b = (const float*)d_in[2];
  const float* ln_g = (const float*)d_in[3];
  const float* ln_b = (const float*)d_in[4];
  const float* exc = (const float*)d_in[5];
  const float* qkv_w = (const float*)d_in[6];
  const float* qkv_b = (const float*)d_in[7];
  const float* op_w = (const float*)d_in[8];
  const float* op_b = (const float*)d_in[9];

  char* ws = (char*)d_ws;
  const size_t MB = 1024ull * 1024ull;
  bf16* ftw_b = (bf16*)(ws + 0);                // 1 MB
  bf16* weff = (bf16*)(ws + 1 * MB);            // 4 MB (q,k rows 0:1024; W_v2 1024:2048)
  bf16* opw_b = (bf16*)(ws + 5 * MB);           // 2 MB
  bf16* wvT = (bf16*)(ws + 7 * MB);             // 2 MB
  float* beff = (float*)(ws + 9 * MB);          // 8 KB
  float* cost = (float*)(ws + 9 * MB + 8192);
  float* sint = (float*)(ws + 9 * MB + 12288);
  float* lcos = (float*)(ws + 9 * MB + 16384);
  float* lsin = (float*)(ws + 9 * MB + 18432);
  bf16* v2T = (bf16*)(ws + 10 * MB);            // 32 MB (4 x 1024 x 4096)
  bf16* qk = (bf16*)(ws + 42 * MB);             // 32 MB (16384 x [q|k])
  bf16* x_b = (bf16*)(ws + 74 * MB);            // 16 MB, dead after stage A
  bf16* gbuf = (bf16*)(ws + 90 * MB);           // 32 MB, dead after LN
  bf16* ubuf = (bf16*)(ws + 122 * MB);          // 32 MB, dead after QKV
  bf16* sc = (bf16*)(ws + 74 * MB);             // 64 MB scores (reuses x_b/gbuf/ubuf)
  float* part0 = (float*)(ws + 138 * MB);       // 16 MB
  float* part1 = (float*)(ws + 154 * MB);       // 16 MB

  cast4_f2b<<<512, 256, 0, stream>>>(ft_w, ftw_b, 131072);
  cast4_f2b<<<1024, 256, 0, stream>>>(op_w, opw_b, 262144);
  cast4_f2b<<<2048, 256, 0, stream>>>(x, x_b, 2097152);
  fold_qkv<<<8192, 256, 0, stream>>>(qkv_w, qkv_b, weff, wvT, beff);
  bias_fold<<<4, 256, 0, stream>>>(op_w, qkv_b, beff);
  tables_kernel<<<4, 256, 0, stream>>>(cost, sint, lcos, lsin, exc);

  // W_v2 = op_w @ W_v -> weff rows 1024:2048
  gemm8p<0, 1><<<dim3(4, 4), 512, 0, stream>>>(opw_b, wvT, weff + 1024 * 1024, nullptr,
                                               nullptr, 1024, 1024, 1024, 1024, 1.0f, 0, 0, 0,
                                               nullptr, nullptr);
  // stage A: g = gelu(x @ ft_w^T + ft_b)
  gemm8p<1, 1><<<dim3(4, 64), 512, 0, stream>>>(x_b, ftw_b, gbuf, nullptr, ft_b, 512, 512,
                                                512, 1024, 1.0f, 0, 0, 0, nullptr, nullptr);
  // LN + phase -> u
  ln_phase_kernel<<<16384, 256, 0, stream>>>(gbuf, ubuf, ln_g, ln_b, lcos, lsin, cost, sint);
  // [qk | V2] = u @ weff^T + beff ; cols 0:1024 -> qk, 1024:2048 -> v2T transposed
  gemm8p<4, 0><<<dim3(8, 64), 512, 0, stream>>>(ubuf, weff, qk, v2T, beff, 1024, 1024, 1024,
                                                1024, 1.0f, 0, 0, 0, nullptr, nullptr);

  float* out0 = (float*)d_out;
  float* out1 = out0 + 8388608LL;
  for (int p = 0; p < 2; ++p) {
    const bf16* qbase = qk + (long long)(2 * p) * 4096 * 1024;
    // S = (q k^T) * D^-0.5, batches 2p, 2p+1
    gemm8p<2, 1><<<dim3(16, 16, 2), 512, 0, stream>>>(
        qbase, qbase + 512, sc, nullptr, nullptr, 512, 1024, 1024, 4096,
        0.04419417382415922f, 4096LL * 1024, 4096LL * 1024, 4096LL * 4096, nullptr, nullptr);
    softmax_kernel<<<8192, 256, 0, stream>>>(sc);
    // out = P @ V2 + op_b; split-K z=4 (2 batches x 2 k-chunks), chunk1 -> partial
    gemm8p<3, 1><<<dim3(4, 16, 4), 512, 0, stream>>>(
        sc, v2T + (long long)(2 * p) * 1024 * 4096, out0, out1, op_b, 2048, 4096, 4096, 0,
        1.0f, 4096LL * 4096, 1024LL * 4096, (long long)(2 * p) * 4096, part0, part1);
    combine_kernel<<<8192, 256, 0, stream>>>(part0, part1,
                                             out0 + (long long)(2 * p) * 4096 * 512,
                                             out1 + (long long)(2 * p) * 4096 * 512);
  }
  (void)in_sizes;
  (void)n_in;
  (void)out_size;
  (void)ws_size;
}

// Round 8
// 530.615 us; speedup vs baseline: 1.7696x; 1.7696x over previous
//
#include <hip/hip_runtime.h>
#include <hip/hip_bf16.h>
#include <math.h>

// QuantumLLM fused pipeline, round 8: 4-phase single-barrier GEMM engine.
// Round 7 falsified the compiler-drain theory (asm reads + sched_barrier = 939us,
// m141-style order-pinning regression). The C++-read engine executes as written at
// 731 TF; the stall is sync density (16 barriers/iter). This round: 4 phases x 1
// barrier (mid-phase barrier proven unnecessary: stage-vs-read separation is
// enforced by end-of-phase barriers + vmcnt ledger). Race audit:
//   M1: read buf0 A[0-7],B[0-1]; stage B(k1)->buf1-B (last read prev-M4, barrier'd)
//   M2: read buf0 B[2-3];        stage A(k2)->buf0-A (last read M1) ; vmcnt(4)
//   M3: read buf1 A[0-7],B[0-1]; stage B(k2)->buf0-B (last read M2)
//   M4: read buf1 B[2-3];        stage A(k3)->buf1-A (last read M3) ; vmcnt(4)
// vmcnt(4) at M2-end retires {A(k1) prev-M4, B(k1) M1} before M3 reads them
// (flight >= 1 phase ~3k cyc > HBM 900); M4-end mirrors for buf0.
// Algebra (rounds 1-4): qkv fold K3072->1024, 4/6 blocks; coll==1 const excitation;
// op_w folded into V so PV writes d_out directly; PV split-K z=4 + combine.

#define TWO_PI_F 6.283185307179586f

typedef __attribute__((ext_vector_type(4))) float f32x4;
typedef __attribute__((ext_vector_type(8))) short bf16x8;
typedef __attribute__((ext_vector_type(4))) unsigned short u16x4;
typedef __hip_bfloat16 bf16;

__device__ __forceinline__ void gl_lds16(const void* g, void* l) {
  __builtin_amdgcn_global_load_lds((const __attribute__((address_space(1))) void*)g,
                                   (__attribute__((address_space(3))) void*)l, 16, 0, 0);
}
__device__ __forceinline__ unsigned short f2bf_bits(float f) {
  union { __hip_bfloat16 h; unsigned short u; } cv;
  cv.h = __float2bfloat16(f);
  return cv.u;
}
__device__ __forceinline__ float bf_bits2f(unsigned short b) {
  union { unsigned int u; float f; } cv;
  cv.u = ((unsigned int)b) << 16;
  return cv.f;
}

#define BAR8()                          \
  asm volatile("" ::: "memory");        \
  __builtin_amdgcn_s_barrier();         \
  asm volatile("" ::: "memory")
#define WAITV4() asm volatile("s_waitcnt vmcnt(4)" ::: "memory")
#define WAITV0() asm volatile("s_waitcnt vmcnt(0)" ::: "memory")

// ============ 4-phase 256x256 GEMM: C = epi(A * B^T * scale + bias) ============
// BM=BN=256, BK=64, 512 thr, 8 waves (2M x 4N), per-wave 128x64 out. LDS 128 KiB
// double-buffered, XOR-swizzled (16B slot ^= row&7) both-sides.
// ORD=1: mfma(b,a) -> lane = C-row, regs = 4 consecutive C-cols (packed stores).
// ORD=0: mfma(a,b) -> regs = 4 consecutive C-rows (for v2T transposed store).
// EPI: 0 bias+bf16; 1 bias+gelu+bf16; 2 scale+bf16 (z batch); 3 PV split-K
//      (z=kchunk*2+batch; chunk0 +bias split fp32 out, chunk1 fp32 partial);
//      4 qkv (col<1024 -> qk, else v2T transposed packed).
template <int EPI, int ORD>
__global__ __launch_bounds__(512, 2) void gemm8p(
    const bf16* __restrict__ A, const bf16* __restrict__ B, void* __restrict__ C,
    void* __restrict__ Cx, const float* __restrict__ bias, int K, int lda, int ldb, int ldc,
    float scale, long long zsa, long long zsb, long long zsc, float* __restrict__ P0,
    float* __restrict__ P1) {
  __shared__ __align__(16) char lds[131072];
  const int tid = threadIdx.x;
  const int lane = tid & 63, wid = tid >> 6;
  const int wm = wid >> 2, wn = wid & 3;

  // XCD-bijective block swizzle (m204)
  const int gx = gridDim.x, gy = gridDim.y, gz = gridDim.z;
  int flat = blockIdx.x + gx * (blockIdx.y + gy * blockIdx.z);
  {
    const int nwg = gx * gy * gz;
    const int q = nwg >> 3, r = nwg & 7;
    const int x = flat & 7, loc = flat >> 3;
    flat = (x < r ? x * (q + 1) : r * (q + 1) + (x - r) * q) + loc;
  }
  const int bx = flat % gx;
  const int by = (flat / gx) % gy;
  const int bz = flat / (gx * gy);
  const int bm = by * 256, bn = bx * 256;

  const bf16 *Az, *Bz;
  if constexpr (EPI == 3) {
    const int b = bz & 1, c = bz >> 1;
    Az = A + (long long)b * zsa + c * 2048;
    Bz = B + (long long)b * zsb + c * 2048;
  } else {
    Az = A + (long long)bz * zsa;
    Bz = B + (long long)bz * zsb;
  }

  f32x4 acc[8][4];
#pragma unroll
  for (int i = 0; i < 8; ++i)
#pragma unroll
    for (int j = 0; j < 4; ++j) acc[i][j] = (f32x4){0.f, 0.f, 0.f, 0.f};

  bf16x8 afr[8][2];
  bf16x8 bfr[2][2];

  // staging constants (write side of the involution)
  const int srow = wid * 16 + (lane >> 3);
  const int sslot = (lane & 7) ^ (lane >> 3);
  const int sldsb = wid * 2048 + lane * 16;

  auto STG = [&](int isA, int buf, int h, int kt) {
#pragma unroll
    for (int l = 0; l < 2; ++l) {
      const int row = h * 128 + srow + l * 8;
      const bf16* src = isA ? Az : Bz;
      const int ld = isA ? lda : ldb;
      const int r0 = isA ? bm : bn;
      const long long g = (long long)(r0 + row) * ld + (long long)kt * 64 + sslot * 8;
      gl_lds16(src + g, &lds[buf * 65536 + (isA ? 0 : 32768) + h * 16384 + sldsb + l * 1024]);
    }
  };

  // ds-read constants (read side, same involution)
  const int rAb = (wm * 128 + (lane & 15)) * 128;
  const int cBb = (wn * 64 + (lane & 15)) * 128;
  const int swzr = (lane & 7) << 4;
  const int kbs = (lane >> 4) << 4;
  const int cby0 = (0 + kbs) ^ swzr;
  const int cby1 = (64 + kbs) ^ swzr;

  auto LDA4 = [&](int buf, int i0) {
    const char* base = &lds[buf * 65536] + rAb;
#pragma unroll
    for (int t = 0; t < 4; ++t) {
      afr[i0 + t][0] = *(const bf16x8*)(base + (i0 + t) * 2048 + cby0);
      afr[i0 + t][1] = *(const bf16x8*)(base + (i0 + t) * 2048 + cby1);
    }
  };
  auto LDB2 = [&](int buf, int j0) {
    const char* base = &lds[buf * 65536 + 32768] + cBb;
#pragma unroll
    for (int t = 0; t < 2; ++t) {
      bfr[t][0] = *(const bf16x8*)(base + (j0 + t) * 2048 + cby0);
      bfr[t][1] = *(const bf16x8*)(base + (j0 + t) * 2048 + cby1);
    }
  };
  auto MFMA16 = [&](int i0, int j0) {
    __builtin_amdgcn_s_setprio(1);
#pragma unroll
    for (int t = 0; t < 4; ++t)
#pragma unroll
      for (int u = 0; u < 2; ++u)
#pragma unroll
        for (int kk = 0; kk < 2; ++kk) {
          if constexpr (ORD == 0)
            acc[i0 + t][j0 + u] = __builtin_amdgcn_mfma_f32_16x16x32_bf16(
                afr[i0 + t][kk], bfr[u][kk], acc[i0 + t][j0 + u], 0, 0, 0);
          else
            acc[i0 + t][j0 + u] = __builtin_amdgcn_mfma_f32_16x16x32_bf16(
                bfr[u][kk], afr[i0 + t][kk], acc[i0 + t][j0 + u], 0, 0, 0);
        }
    __builtin_amdgcn_s_setprio(0);
  };

  const int nkt = K >> 6;
  const int nit = nkt >> 1;

  // prologue: buf0 A(k0)+B(k0) (8 loads), buf1 A(k1) (4 loads); retire buf0's 8.
  STG(1, 0, 0, 0);
  STG(1, 0, 1, 0);
  STG(0, 0, 0, 0);
  STG(0, 0, 1, 0);
  STG(1, 1, 0, 1);
  STG(1, 1, 1, 1);
  WAITV4();
  BAR8();

  for (int i = 0; i < nit; ++i) {
    const int k1 = 2 * i + 1;
    const int k2t = 2 * i + 2, k3t = 2 * i + 3;
    const int k2 = (k2t < nkt) ? k2t : 0;
    const int k3 = (k3t < nkt) ? k3t : 0;
    // M1: read buf0 A[0-7],B[0-1]; stage B(k1)->buf1-B (free since prev-M4 barrier)
    LDA4(0, 0);
    LDA4(0, 4);
    LDB2(0, 0);
    STG(0, 1, 0, k1);
    STG(0, 1, 1, k1);
    MFMA16(0, 0);
    MFMA16(4, 0);
    BAR8();
    // M2: read buf0 B[2-3]; stage A(k2)->buf0-A (read finished in M1);
    //     vmcnt(4) retires {A(k1) prev-M4, B(k1) M1} for M3's reads
    LDB2(0, 2);
    STG(1, 0, 0, k2);
    STG(1, 0, 1, k2);
    MFMA16(0, 2);
    MFMA16(4, 2);
    WAITV4();
    BAR8();
    // M3: read buf1 A[0-7],B[0-1]; stage B(k2)->buf0-B (read finished in M2)
    LDA4(1, 0);
    LDA4(1, 4);
    LDB2(1, 0);
    STG(0, 0, 0, k2);
    STG(0, 0, 1, k2);
    MFMA16(0, 0);
    MFMA16(4, 0);
    BAR8();
    // M4: read buf1 B[2-3]; stage A(k3)->buf1-A (read finished in M3);
    //     vmcnt(4) retires {A(k2) M2, B(k2) M3} for next-M1's reads
    LDB2(1, 2);
    STG(1, 1, 0, k3);
    STG(1, 1, 1, k3);
    MFMA16(0, 2);
    MFMA16(4, 2);
    WAITV4();
    BAR8();
  }
  WAITV0();  // drain remaining DMA before epilogue/endpgm

  // ---- epilogue ----
  const int fr = lane & 15, ksl = lane >> 4;
#pragma unroll
  for (int i = 0; i < 8; ++i)
#pragma unroll
    for (int j = 0; j < 4; ++j) {
      if constexpr (ORD == 1) {
        // lane fr = row, regs = 4 consecutive cols
        const int row = bm + wm * 128 + i * 16 + fr;
        const int col0 = bn + wn * 64 + j * 16 + ksl * 4;
        f32x4 v = acc[i][j];
#pragma unroll
        for (int r = 0; r < 4; ++r) v[r] *= scale;
        if constexpr (EPI == 0 || EPI == 1) {
          if (bias) {
            const f32x4 bv = *(const f32x4*)&bias[col0];
            v += bv;
          }
        }
        if constexpr (EPI == 1) {
#pragma unroll
          for (int r = 0; r < 4; ++r) {
            const float t = v[r];
            float y = 0.7978845608028654f * (t + 0.044715f * t * t * t);
            y = fminf(fmaxf(y, -15.f), 15.f);
            const float e = __expf(2.f * y);
            v[r] = t * e / (1.f + e);
          }
        }
        if constexpr (EPI == 3) {
          const int b = bz & 1, c = bz >> 1;
          if (c == 0) {
            const f32x4 bv = *(const f32x4*)&bias[col0];
            v += bv;
            float* dst = (col0 < 512) ? (float*)C : (float*)Cx;
            const long long rbase = zsc + (long long)b * 4096 + row;
            *(f32x4*)&dst[rbase * 512 + (col0 & 511)] = v;
          } else {
            float* dst = b ? P1 : P0;
            *(f32x4*)&dst[(long long)row * 1024 + col0] = v;
          }
        } else {
          bf16* cc = (bf16*)C;
          if constexpr (EPI == 2) cc += (long long)bz * zsc;
          u16x4 w;
#pragma unroll
          for (int r = 0; r < 4; ++r) w[r] = f2bf_bits(v[r]);
          *(u16x4*)&cc[(long long)row * ldc + col0] = w;
        }
      } else {
        // ORD==0 (EPI 4): regs = 4 consecutive rows, lane fr = col
        const int row0 = bm + wm * 128 + i * 16 + ksl * 4;
        const int col = bn + wn * 64 + j * 16 + fr;
        float v[4];
#pragma unroll
        for (int r = 0; r < 4; ++r) {
          v[r] = acc[i][j][r] * scale;
          if (bias) v[r] += bias[col];
        }
        if (col < 1024) {
          bf16* cc = (bf16*)C;
#pragma unroll
          for (int r = 0; r < 4; ++r)
            cc[(long long)(row0 + r) * 1024 + col] = __float2bfloat16(v[r]);
        } else {
          const int d = col - 1024, b = row0 >> 12, mm = row0 & 4095;
          u16x4 w;
#pragma unroll
          for (int r = 0; r < 4; ++r) w[r] = f2bf_bits(v[r]);
          *(u16x4*)((unsigned short*)Cx + ((long long)(b * 1024 + d)) * 4096 + mm) = w;
        }
      }
    }
}

// ---------------- combine: out += partial (one batch-pair) ----------------
__global__ __launch_bounds__(256) void combine_kernel(const float* __restrict__ p0,
                                                      const float* __restrict__ p1,
                                                      float* __restrict__ out0,
                                                      float* __restrict__ out1) {
  const int idx = blockIdx.x * 256 + threadIdx.x;
  const int b = idx >> 20;
  const int rem = idx & 1048575;
  const int row = rem >> 8;
  const int c4 = rem & 255;
  const float* p = b ? p1 : p0;
  const f32x4 v = *(const f32x4*)(p + (long long)row * 1024 + c4 * 4);
  float* dst = (c4 < 128) ? out0 : out1;
  const long long o = ((long long)(b * 4096 + row)) * 512 + (c4 & 127) * 4;
  f32x4 d = *(f32x4*)(dst + o);
  d += v;
  *(f32x4*)(dst + o) = d;
}

// ---------------- LayerNorm + phase ops ----------------
__global__ __launch_bounds__(256) void ln_phase_kernel(
    const bf16* __restrict__ g, bf16* __restrict__ u, const float* __restrict__ ln_g,
    const float* __restrict__ ln_b, const float* __restrict__ lcos,
    const float* __restrict__ lsin, const float* __restrict__ cost,
    const float* __restrict__ sint) {
  __shared__ float sg[1024];
  __shared__ float red[4];
  const int tid = threadIdx.x;
  const int lane = tid & 63, wid = tid >> 6;
  const long long row = blockIdx.x;
  const bf16* gr = g + row * 1024;

  const u16x4 raw = *(const u16x4*)(gr + tid * 4);
  float lv[4];
  float lsum = 0.f;
#pragma unroll
  for (int e = 0; e < 4; ++e) {
    lv[e] = bf_bits2f(raw[e]);
    lsum += lv[e];
  }
  *(f32x4*)&sg[tid * 4] = *(f32x4*)lv;
#pragma unroll
  for (int off = 32; off > 0; off >>= 1) lsum += __shfl_xor(lsum, off);
  if (lane == 0) red[wid] = lsum;
  __syncthreads();
  const float mu = (red[0] + red[1] + red[2] + red[3]) * (1.0f / 1024.0f);
  __syncthreads();
  float lvar = 0.f;
#pragma unroll
  for (int e = 0; e < 4; ++e) {
    const float d = lv[e] - mu;
    lvar += d * d;
  }
#pragma unroll
  for (int off = 32; off > 0; off >>= 1) lvar += __shfl_xor(lvar, off);
  if (lane == 0) red[wid] = lvar;
  __syncthreads();
  const float var = (red[0] + red[1] + red[2] + red[3]) * (1.0f / 1024.0f);
  const float rs = rsqrtf(var + 1e-5f);

#pragma unroll
  for (int kk = 0; kk < 2; ++kk) {
    const int p = tid + kk * 256;
    const float rp = (sg[p] - mu) * rs * ln_g[p] + ln_b[p];
    const float ip = (sg[p + 512] - mu) * rs * ln_g[p + 512] + ln_b[p + 512];
    const float ang = atan2f(ip + 1e-8f, rp + 1e-8f);
    int idx = (int)((ang / TWO_PI_F) * 1023.0f);
    idx = idx < 0 ? idx + 1024 : idx;
    float real = rp * cost[idx];
    float imag = ip * sint[idx];
    const float nrm = rsqrtf(real * real + imag * imag + 1e-8f) * 0.044194173824159216f;
    real *= nrm;
    imag *= nrm;
    const float amp = sqrtf(real * real + imag * imag + 1e-8f);
    const float coll = (amp < 0.1f) ? 1.0f : 0.0f;
    real += coll * lcos[p];
    imag += coll * lsin[p];
    const float n2 = rsqrtf(real * real + imag * imag + 1e-8f);
    u[row * 1024 + p] = __float2bfloat16(real * n2);
    u[row * 1024 + 512 + p] = __float2bfloat16(imag * n2);
  }
}

// ---------------- rowwise softmax in place on bf16 scores ----------------
__global__ __launch_bounds__(256) void softmax_kernel(bf16* __restrict__ s) {
  __shared__ float ss[4096];
  __shared__ float red[4];
  const int tid = threadIdx.x;
  const int lane = tid & 63, wid = tid >> 6;
  bf16* sr = s + (long long)blockIdx.x * 4096;
  float mx = -3.0e38f;
#pragma unroll
  for (int k = 0; k < 4; ++k) {
    const int base = (k * 256 + tid) * 4;
    const u16x4 raw = *(const u16x4*)(sr + base);
    f32x4 f;
#pragma unroll
    for (int e = 0; e < 4; ++e) {
      f[e] = bf_bits2f(raw[e]);
      mx = fmaxf(mx, f[e]);
    }
    *(f32x4*)&ss[base] = f;
  }
#pragma unroll
  for (int off = 32; off > 0; off >>= 1) mx = fmaxf(mx, __shfl_xor(mx, off));
  if (lane == 0) red[wid] = mx;
  __syncthreads();
  mx = fmaxf(fmaxf(red[0], red[1]), fmaxf(red[2], red[3]));
  __syncthreads();
  float sum = 0.f;
#pragma unroll
  for (int k = 0; k < 4; ++k) {
    const int base = (k * 256 + tid) * 4;
    f32x4 f = *(f32x4*)&ss[base];
#pragma unroll
    for (int e = 0; e < 4; ++e) {
      f[e] = __expf(f[e] - mx);
      sum += f[e];
    }
    *(f32x4*)&ss[base] = f;
  }
#pragma unroll
  for (int off = 32; off > 0; off >>= 1) sum += __shfl_xor(sum, off);
  if (lane == 0) red[wid] = sum;
  __syncthreads();
  const float inv = 1.0f / (red[0] + red[1] + red[2] + red[3]);
#pragma unroll
  for (int k = 0; k < 4; ++k) {
    const int base = (k * 256 + tid) * 4;
    const f32x4 f = *(f32x4*)&ss[base];
    u16x4 w;
#pragma unroll
    for (int e = 0; e < 4; ++e) w[e] = f2bf_bits(f[e] * inv);
    *(u16x4*)(sr + base) = w;
  }
}

// ---------------- prep ----------------
__global__ void cast4_f2b(const float* __restrict__ in, bf16* __restrict__ out, long long n4) {
  long long i = (long long)blockIdx.x * blockDim.x + threadIdx.x;
  const long long stride = (long long)gridDim.x * blockDim.x;
  for (; i < n4; i += stride) {
    const f32x4 f = *(const f32x4*)(in + i * 4);
    u16x4 w;
#pragma unroll
    for (int e = 0; e < 4; ++e) w[e] = f2bf_bits(f[e]);
    *(u16x4*)((unsigned short*)out + i * 4) = w;
  }
}

__global__ void fold_qkv(const float* __restrict__ w, const float* __restrict__ b,
                         bf16* __restrict__ weff, bf16* __restrict__ wvT,
                         float* __restrict__ beff) {
  const int i = blockIdx.x * blockDim.x + threadIdx.x;
  if (i < 2048 * 1024) {
    const int o = i >> 10, j = i & 1023;
    if (o < 1024) {
      const int so = (o < 512) ? o : o + 512;
      const float* wr = w + (long long)so * 3072;
      weff[i] = __float2bfloat16(wr[j] + wr[1024 + j] + wr[2048 + j]);
      if (j == 0) beff[o] = b[so];
    } else {
      const int t = o - 1024;
      const float* wr = w + (long long)(2048 + t) * 3072;
      wvT[(long long)j * 1024 + t] = __float2bfloat16(wr[j] + wr[1024 + j] + wr[2048 + j]);
    }
  }
}

__global__ void bias_fold(const float* __restrict__ op_w, const float* __restrict__ qkv_b,
                          float* __restrict__ beff) {
  const int o = blockIdx.x * blockDim.x + threadIdx.x;
  if (o < 1024) {
    const float* wr = op_w + (long long)o * 1024;
    float s = 0.f;
    for (int t = 0; t < 1024; ++t) s += wr[t] * qkv_b[2048 + t];
    beff[1024 + o] = s;
  }
}

__global__ void tables_kernel(float* __restrict__ cost, float* __restrict__ sint,
                              float* __restrict__ lcos, float* __restrict__ lsin,
                              const float* __restrict__ exc) {
  const int i = blockIdx.x * blockDim.x + threadIdx.x;
  const double step = 6.283185307179586 / 1023.0;
  if (i < 1024) {
    const float a = (float)((double)i * step);
    cost[i] = cosf(a);
    sint[i] = sinf(a);
  }
  if (i < 512) {
    const float el = ((float)i / 511.0f) * TWO_PI_F;
    const float m = fmodf(el, TWO_PI_F);
    int li = (int)((m / TWO_PI_F) * 1024.0f);
    li = min(max(li, 0), 1023);
    const float a = (float)((double)li * step);
    lcos[i] = cosf(a) * exc[0];
    lsin[i] = sinf(a) * exc[0];
  }
}

extern "C" void kernel_launch(void* const* d_in, const int* in_sizes, int n_in, void* d_out,
                              int out_size, void* d_ws, size_t ws_size, hipStream_t stream) {
  const float* x = (const float*)d_in[0];
  const float* ft_w = (const float*)d_in[1];
  const float* ft_b = (const float*)d_in[2];
  const float* ln_g = (const float*)d_in[3];
  const float* ln_b = (const float*)d_in[4];
  const float* exc = (const float*)d_in[5];
  const float* qkv_w = (const float*)d_in[6];
  const float* qkv_b = (const float*)d_in[7];
  const float* op_w = (const float*)d_in[8];
  const float* op_b = (const float*)d_in[9];

  char* ws = (char*)d_ws;
  const size_t MB = 1024ull * 1024ull;
  bf16* ftw_b = (bf16*)(ws + 0);                // 1 MB
  bf16* weff = (bf16*)(ws + 1 * MB);            // 4 MB (q,k rows 0:1024; W_v2 1024:2048)
  bf16* opw_b = (bf16*)(ws + 5 * MB);           // 2 MB
  bf16* wvT = (bf16*)(ws + 7 * MB);             // 2 MB
  float* beff = (float*)(ws + 9 * MB);          // 8 KB
  float* cost = (float*)(ws + 9 * MB + 8192);
  float* sint = (float*)(ws + 9 * MB + 12288);
  float* lcos = (float*)(ws + 9 * MB + 16384);
  float* lsin = (float*)(ws + 9 * MB + 18432);
  bf16* v2T = (bf16*)(ws + 10 * MB);            // 32 MB (4 x 1024 x 4096)
  bf16* qk = (bf16*)(ws + 42 * MB);             // 32 MB (16384 x [q|k])
  bf16* x_b = (bf16*)(ws + 74 * MB);            // 16 MB, dead after stage A
  bf16* gbuf = (bf16*)(ws + 90 * MB);           // 32 MB, dead after LN
  bf16* ubuf = (bf16*)(ws + 122 * MB);          // 32 MB, dead after QKV
  bf16* sc = (bf16*)(ws + 74 * MB);             // 64 MB scores (reuses x_b/gbuf/ubuf)
  float* part0 = (float*)(ws + 138 * MB);       // 16 MB
  float* part1 = (float*)(ws + 154 * MB);       // 16 MB

  cast4_f2b<<<512, 256, 0, stream>>>(ft_w, ftw_b, 131072);
  cast4_f2b<<<1024, 256, 0, stream>>>(op_w, opw_b, 262144);
  cast4_f2b<<<2048, 256, 0, stream>>>(x, x_b, 2097152);
  fold_qkv<<<8192, 256, 0, stream>>>(qkv_w, qkv_b, weff, wvT, beff);
  bias_fold<<<4, 256, 0, stream>>>(op_w, qkv_b, beff);
  tables_kernel<<<4, 256, 0, stream>>>(cost, sint, lcos, lsin, exc);

  // W_v2 = op_w @ W_v -> weff rows 1024:2048
  gemm8p<0, 1><<<dim3(4, 4), 512, 0, stream>>>(opw_b, wvT, weff + 1024 * 1024, nullptr,
                                               nullptr, 1024, 1024, 1024, 1024, 1.0f, 0, 0, 0,
                                               nullptr, nullptr);
  // stage A: g = gelu(x @ ft_w^T + ft_b)
  gemm8p<1, 1><<<dim3(4, 64), 512, 0, stream>>>(x_b, ftw_b, gbuf, nullptr, ft_b, 512, 512,
                                                512, 1024, 1.0f, 0, 0, 0, nullptr, nullptr);
  // LN + phase -> u
  ln_phase_kernel<<<16384, 256, 0, stream>>>(gbuf, ubuf, ln_g, ln_b, lcos, lsin, cost, sint);
  // [qk | V2] = u @ weff^T + beff ; cols 0:1024 -> qk, 1024:2048 -> v2T transposed
  gemm8p<4, 0><<<dim3(8, 64), 512, 0, stream>>>(ubuf, weff, qk, v2T, beff, 1024, 1024, 1024,
                                                1024, 1.0f, 0, 0, 0, nullptr, nullptr);

  float* out0 = (float*)d_out;
  float* out1 = out0 + 8388608LL;
  for (int p = 0; p < 2; ++p) {
    const bf16* qbase = qk + (long long)(2 * p) * 4096 * 1024;
    // S = (q k^T) * D^-0.5, batches 2p, 2p+1
    gemm8p<2, 1><<<dim3(16, 16, 2), 512, 0, stream>>>(
        qbase, qbase + 512, sc, nullptr, nullptr, 512, 1024, 1024, 4096,
        0.04419417382415922f, 4096LL * 1024, 4096LL * 1024, 4096LL * 4096, nullptr, nullptr);
    softmax_kernel<<<8192, 256, 0, stream>>>(sc);
    // out = P @ V2 + op_b; split-K z=4 (2 batches x 2 k-chunks), chunk1 -> partial
    gemm8p<3, 1><<<dim3(4, 16, 4), 512, 0, stream>>>(
        sc, v2T + (long long)(2 * p) * 1024 * 4096, out0, out1, op_b, 2048, 4096, 4096, 0,
        1.0f, 4096LL * 4096, 1024LL * 4096, (long long)(2 * p) * 4096, part0, part1);
    combine_kernel<<<8192, 256, 0, stream>>>(part0, part1,
                                             out0 + (long long)(2 * p) * 4096 * 512,
                                             out1 + (long long)(2 * p) * 4096 * 512);
  }
  (void)in_sizes;
  (void)n_in;
  (void)out_size;
  (void)ws_size;
}

// Round 9
// 525.801 us; speedup vs baseline: 1.7859x; 1.0092x over previous
//
#include <hip/hip_runtime.h>
#include <hip/hip_bf16.h>
#include <math.h>

// QuantumLLM fused pipeline, round 9: back to the 128^2 m97-structure engine
// (3 blocks/CU -> cross-block latency hiding, the mechanism the 1-block/CU 256^2
// engine lacks; rounds 3-8 proved its schedule variants all stall at ~30% MfmaUtil).
// Fixes vs round-1/2's 128^2: (a) both-sides XOR swizzle (was 8-way bank conflict,
// 8.4M/dispatch); (b) packed epilogue stores via MFMA operand swap (was 128
// scattered 2B stores/lane). Structural: QKV split into qk(packed) + v2T dispatches;
// PV has NO split-K (z=2, K=4096, 512 blocks co-resident at 3 blk/CU) -> combine
// and partial buffers deleted; fold_v via tiled transpose; bias_fold parallel.
// Algebra (rounds 1-4): qkv fold K3072->1024, 4/6 blocks; coll==1 const excitation;
// op_w folded into V so PV writes d_out directly.

#define TWO_PI_F 6.283185307179586f

typedef __attribute__((ext_vector_type(4))) float f32x4;
typedef __attribute__((ext_vector_type(8))) short bf16x8;
typedef __attribute__((ext_vector_type(4))) unsigned short u16x4;
typedef __hip_bfloat16 bf16;

__device__ __forceinline__ void gl_lds16(const void* g, void* l) {
  __builtin_amdgcn_global_load_lds((const __attribute__((address_space(1))) void*)g,
                                   (__attribute__((address_space(3))) void*)l, 16, 0, 0);
}
__device__ __forceinline__ unsigned short f2bf_bits(float f) {
  union { __hip_bfloat16 h; unsigned short u; } cv;
  cv.h = __float2bfloat16(f);
  return cv.u;
}
__device__ __forceinline__ float bf_bits2f(unsigned short b) {
  union { unsigned int u; float f; } cv;
  cv.u = ((unsigned int)b) << 16;
  return cv.f;
}

// ============ 128x128 GEMM (m97 structure): C = epi(A * B^T * scale + bias) ====
// 4 waves (2x2), per-wave 64x64 = 4x4 mfma_f32_16x16x32_bf16. BK=32, 16 KB LDS,
// single-buffered stage->sync->read->MFMA->sync. ~3 blocks/CU co-resident.
// LDS swizzle: 16B slot ^= (row&3)^((row>>2)&3), applied to the staged GLOBAL
// source (linear DMA dest) and to the ds_read address => uniform 2-way (free).
// ORD=1: mfma(b,a) -> lane = C-row, regs = 4 consecutive C-cols (packed stores).
// ORD=0: mfma(a,b) -> regs = 4 consecutive C-rows (for v2T transposed store).
// EPI: 0 bias+bf16; 1 bias+gelu+bf16; 2 scale+bf16 (z batch); 3 PV full-K
//      (z batch; bias + split fp32 direct to d_out); 4 v2T transposed (ORD=0).
template <int EPI, int ORD>
__global__ __launch_bounds__(256, 2) void gemm128(
    const bf16* __restrict__ A, const bf16* __restrict__ B, void* __restrict__ C,
    void* __restrict__ Cx, const float* __restrict__ bias, int K, int lda, int ldb, int ldc,
    float scale, long long zsa, long long zsb, long long zsc) {
  __shared__ __align__(16) bf16 sA[128 * 32];
  __shared__ __align__(16) bf16 sB[128 * 32];
  const int tid = threadIdx.x;
  const int lane = tid & 63, wid = tid >> 6;
  const int wm = wid >> 1, wn = wid & 1;

  // XCD-bijective block swizzle (m204)
  const int gx = gridDim.x, gy = gridDim.y;
  int flat = blockIdx.x + gx * (blockIdx.y + gy * blockIdx.z);
  {
    const int nwg = gx * gy * gridDim.z;
    const int q = nwg >> 3, r = nwg & 7;
    const int x = flat & 7, loc = flat >> 3;
    flat = (x < r ? x * (q + 1) : r * (q + 1) + (x - r) * q) + loc;
  }
  const int bx = flat % gx;
  const int by = (flat / gx) % gy;
  const int bz = flat / (gx * gy);
  const int bm = by * 128, bn = bx * 128;

  const bf16* Az = A + (long long)bz * zsa;
  const bf16* Bz = B + (long long)bz * zsb;

  f32x4 acc[4][4];
#pragma unroll
  for (int i = 0; i < 4; ++i)
#pragma unroll
    for (int j = 0; j < 4; ++j) acc[i][j] = (f32x4){0.f, 0.f, 0.f, 0.f};

  // staging: thread c in {tid, tid+256}: lds row c>>2, slot c&3 (linear DMA dest);
  // global k-offset pre-swizzled so lds[r][s] = G[r][s ^ swz(r)].
  const int r0 = tid >> 2, r1 = (tid + 256) >> 2, sl = tid & 3;
  const int swzr0 = (r0 & 3) ^ ((r0 >> 2) & 3);
  const int swzr1 = (r1 & 3) ^ ((r1 >> 2) & 3);
  const int ga0 = (sl ^ swzr0) << 3;  // element offset within K-tile
  const int ga1 = (sl ^ swzr1) << 3;
  const long long rowA0 = (long long)(bm + r0) * lda;
  const long long rowA1 = (long long)(bm + r1) * lda;
  const long long rowB0 = (long long)(bn + r0) * ldb;
  const long long rowB1 = (long long)(bn + r1) * ldb;

  const int fr = lane & 15, ksl = lane >> 4;

  for (int k0 = 0; k0 < K; k0 += 32) {
    gl_lds16(Az + rowA0 + k0 + ga0, &sA[tid * 8]);
    gl_lds16(Az + rowA1 + k0 + ga1, &sA[(tid + 256) * 8]);
    gl_lds16(Bz + rowB0 + k0 + ga0, &sB[tid * 8]);
    gl_lds16(Bz + rowB1 + k0 + ga1, &sB[(tid + 256) * 8]);
    __syncthreads();
    bf16x8 af[4], bfv[4];
#pragma unroll
    for (int i = 0; i < 4; ++i) {
      const int R = wm * 64 + i * 16 + fr;
      const int s = ksl ^ ((R & 3) ^ ((R >> 2) & 3));
      af[i] = *(const bf16x8*)&sA[R * 32 + s * 8];
    }
#pragma unroll
    for (int j = 0; j < 4; ++j) {
      const int R = wn * 64 + j * 16 + fr;
      const int s = ksl ^ ((R & 3) ^ ((R >> 2) & 3));
      bfv[j] = *(const bf16x8*)&sB[R * 32 + s * 8];
    }
#pragma unroll
    for (int i = 0; i < 4; ++i)
#pragma unroll
      for (int j = 0; j < 4; ++j) {
        if constexpr (ORD == 0)
          acc[i][j] = __builtin_amdgcn_mfma_f32_16x16x32_bf16(af[i], bfv[j], acc[i][j], 0, 0, 0);
        else
          acc[i][j] = __builtin_amdgcn_mfma_f32_16x16x32_bf16(bfv[j], af[i], acc[i][j], 0, 0, 0);
      }
    __syncthreads();
  }

  // ---- epilogue ----
#pragma unroll
  for (int i = 0; i < 4; ++i)
#pragma unroll
    for (int j = 0; j < 4; ++j) {
      if constexpr (ORD == 1) {
        // lane fr = C-row, regs = 4 consecutive C-cols
        const int row = bm + wm * 64 + i * 16 + fr;
        const int col0 = bn + wn * 64 + j * 16 + ksl * 4;
        f32x4 v = acc[i][j];
#pragma unroll
        for (int r = 0; r < 4; ++r) v[r] *= scale;
        if constexpr (EPI == 0 || EPI == 1) {
          if (bias) {
            const f32x4 bv = *(const f32x4*)&bias[col0];
            v += bv;
          }
        }
        if constexpr (EPI == 1) {
#pragma unroll
          for (int r = 0; r < 4; ++r) {
            const float t = v[r];
            float y = 0.7978845608028654f * (t + 0.044715f * t * t * t);
            y = fminf(fmaxf(y, -15.f), 15.f);
            const float e = __expf(2.f * y);
            v[r] = t * e / (1.f + e);
          }
        }
        if constexpr (EPI == 3) {
          const f32x4 bv = *(const f32x4*)&bias[col0];
          v += bv;
          float* dst = (col0 < 512) ? (float*)C : (float*)Cx;
          const long long rout = zsc + (long long)bz * 4096 + row;
          *(f32x4*)&dst[rout * 512 + (col0 & 511)] = v;
        } else if constexpr (EPI == 2) {
          bf16* cc = (bf16*)C + (long long)bz * zsc;
          u16x4 w;
#pragma unroll
          for (int r = 0; r < 4; ++r) w[r] = f2bf_bits(v[r]);
          *(u16x4*)&cc[(long long)row * ldc + col0] = w;
        } else {
          bf16* cc = (bf16*)C;
          u16x4 w;
#pragma unroll
          for (int r = 0; r < 4; ++r) w[r] = f2bf_bits(v[r]);
          *(u16x4*)&cc[(long long)row * ldc + col0] = w;
        }
      } else {
        // ORD==0 (EPI 4, v2T): regs = 4 consecutive rows, lane fr = v2-col d
        const int row0 = bm + wm * 64 + i * 16 + ksl * 4;
        const int d = bn + wn * 64 + j * 16 + fr;
        u16x4 w;
#pragma unroll
        for (int r = 0; r < 4; ++r) w[r] = f2bf_bits(acc[i][j][r] * scale + bias[d]);
        const int b = row0 >> 12, mm = row0 & 4095;
        *(u16x4*)((unsigned short*)Cx + ((long long)(b * 1024 + d)) * 4096 + mm) = w;
      }
    }
  (void)ldc;
}

// ---------------- LayerNorm + phase ops ----------------
__global__ __launch_bounds__(256) void ln_phase_kernel(
    const bf16* __restrict__ g, bf16* __restrict__ u, const float* __restrict__ ln_g,
    const float* __restrict__ ln_b, const float* __restrict__ lcos,
    const float* __restrict__ lsin, const float* __restrict__ cost,
    const float* __restrict__ sint) {
  __shared__ float sg[1024];
  __shared__ float red[4];
  const int tid = threadIdx.x;
  const int lane = tid & 63, wid = tid >> 6;
  const long long row = blockIdx.x;
  const bf16* gr = g + row * 1024;

  const u16x4 raw = *(const u16x4*)(gr + tid * 4);
  float lv[4];
  float lsum = 0.f;
#pragma unroll
  for (int e = 0; e < 4; ++e) {
    lv[e] = bf_bits2f(raw[e]);
    lsum += lv[e];
  }
  *(f32x4*)&sg[tid * 4] = *(f32x4*)lv;
#pragma unroll
  for (int off = 32; off > 0; off >>= 1) lsum += __shfl_xor(lsum, off);
  if (lane == 0) red[wid] = lsum;
  __syncthreads();
  const float mu = (red[0] + red[1] + red[2] + red[3]) * (1.0f / 1024.0f);
  __syncthreads();
  float lvar = 0.f;
#pragma unroll
  for (int e = 0; e < 4; ++e) {
    const float d = lv[e] - mu;
    lvar += d * d;
  }
#pragma unroll
  for (int off = 32; off > 0; off >>= 1) lvar += __shfl_xor(lvar, off);
  if (lane == 0) red[wid] = lvar;
  __syncthreads();
  const float var = (red[0] + red[1] + red[2] + red[3]) * (1.0f / 1024.0f);
  const float rs = rsqrtf(var + 1e-5f);

#pragma unroll
  for (int kk = 0; kk < 2; ++kk) {
    const int p = tid + kk * 256;
    const float rp = (sg[p] - mu) * rs * ln_g[p] + ln_b[p];
    const float ip = (sg[p + 512] - mu) * rs * ln_g[p + 512] + ln_b[p + 512];
    const float ang = atan2f(ip + 1e-8f, rp + 1e-8f);
    int idx = (int)((ang / TWO_PI_F) * 1023.0f);
    idx = idx < 0 ? idx + 1024 : idx;
    float real = rp * cost[idx];
    float imag = ip * sint[idx];
    const float nrm = rsqrtf(real * real + imag * imag + 1e-8f) * 0.044194173824159216f;
    real *= nrm;
    imag *= nrm;
    const float amp = sqrtf(real * real + imag * imag + 1e-8f);
    const float coll = (amp < 0.1f) ? 1.0f : 0.0f;
    real += coll * lcos[p];
    imag += coll * lsin[p];
    const float n2 = rsqrtf(real * real + imag * imag + 1e-8f);
    u[row * 1024 + p] = __float2bfloat16(real * n2);
    u[row * 1024 + 512 + p] = __float2bfloat16(imag * n2);
  }
}

// ---------------- rowwise softmax in place on bf16 scores ----------------
__global__ __launch_bounds__(256) void softmax_kernel(bf16* __restrict__ s) {
  __shared__ float ss[4096];
  __shared__ float red[4];
  const int tid = threadIdx.x;
  const int lane = tid & 63, wid = tid >> 6;
  bf16* sr = s + (long long)blockIdx.x * 4096;
  float mx = -3.0e38f;
#pragma unroll
  for (int k = 0; k < 4; ++k) {
    const int base = (k * 256 + tid) * 4;
    const u16x4 raw = *(const u16x4*)(sr + base);
    f32x4 f;
#pragma unroll
    for (int e = 0; e < 4; ++e) {
      f[e] = bf_bits2f(raw[e]);
      mx = fmaxf(mx, f[e]);
    }
    *(f32x4*)&ss[base] = f;
  }
#pragma unroll
  for (int off = 32; off > 0; off >>= 1) mx = fmaxf(mx, __shfl_xor(mx, off));
  if (lane == 0) red[wid] = mx;
  __syncthreads();
  mx = fmaxf(fmaxf(red[0], red[1]), fmaxf(red[2], red[3]));
  __syncthreads();
  float sum = 0.f;
#pragma unroll
  for (int k = 0; k < 4; ++k) {
    const int base = (k * 256 + tid) * 4;
    f32x4 f = *(f32x4*)&ss[base];
#pragma unroll
    for (int e = 0; e < 4; ++e) {
      f[e] = __expf(f[e] - mx);
      sum += f[e];
    }
    *(f32x4*)&ss[base] = f;
  }
#pragma unroll
  for (int off = 32; off > 0; off >>= 1) sum += __shfl_xor(sum, off);
  if (lane == 0) red[wid] = sum;
  __syncthreads();
  const float inv = 1.0f / (red[0] + red[1] + red[2] + red[3]);
#pragma unroll
  for (int k = 0; k < 4; ++k) {
    const int base = (k * 256 + tid) * 4;
    const f32x4 f = *(f32x4*)&ss[base];
    u16x4 w;
#pragma unroll
    for (int e = 0; e < 4; ++e) w[e] = f2bf_bits(f[e] * inv);
    *(u16x4*)(sr + base) = w;
  }
}

// ---------------- prep ----------------
__global__ void cast4_f2b(const float* __restrict__ in, bf16* __restrict__ out, long long n4) {
  long long i = (long long)blockIdx.x * blockDim.x + threadIdx.x;
  const long long stride = (long long)gridDim.x * blockDim.x;
  for (; i < n4; i += stride) {
    const f32x4 f = *(const f32x4*)(in + i * 4);
    u16x4 w;
#pragma unroll
    for (int e = 0; e < 4; ++e) w[e] = f2bf_bits(f[e]);
    *(u16x4*)((unsigned short*)out + i * 4) = w;
  }
}

// weff rows [0,512)=q (qkv rows 0:512), [512,1024)=k (rows 1024:1536); + beff[0:1024]
__global__ void fold_qkv(const float* __restrict__ w, const float* __restrict__ b,
                         bf16* __restrict__ weff, float* __restrict__ beff) {
  const int i = blockIdx.x * blockDim.x + threadIdx.x;
  if (i < 1024 * 1024) {
    const int o = i >> 10, j = i & 1023;
    const int so = (o < 512) ? o : o + 512;
    const float* wr = w + (long long)so * 3072;
    weff[i] = __float2bfloat16(wr[j] + wr[1024 + j] + wr[2048 + j]);
    if (j == 0) beff[o] = b[so];
  }
}

// wvT[j][t] = sum_c qkv_w[2048+t][j+1024c], via 32x32 LDS tile (coalesced both sides)
__global__ __launch_bounds__(256) void fold_v_t(const float* __restrict__ w,
                                                bf16* __restrict__ wvT) {
  __shared__ float tile[32][33];
  const int t0 = blockIdx.x * 32, j0 = blockIdx.y * 32;
  const int tx = threadIdx.x & 31, ty = threadIdx.x >> 5;
#pragma unroll
  for (int k = 0; k < 4; ++k) {
    const int t = t0 + ty + k * 8;
    const float* wr = w + (long long)(2048 + t) * 3072 + j0 + tx;
    tile[ty + k * 8][tx] = wr[0] + wr[1024] + wr[2048];
  }
  __syncthreads();
#pragma unroll
  for (int k = 0; k < 4; ++k) {
    const int r = ty + k * 8;
    wvT[(long long)(j0 + r) * 1024 + t0 + tx] = __float2bfloat16(tile[tx][r]);
  }
}

// beff[1024+o] = sum_t op_w[o][t] * qkv_b[2048+t], one block per o
__global__ __launch_bounds__(256) void bias_fold2(const float* __restrict__ op_w,
                                                  const float* __restrict__ qkv_b,
                                                  float* __restrict__ beff) {
  __shared__ float red[4];
  const int o = blockIdx.x;
  const int tid = threadIdx.x, lane = tid & 63, wid = tid >> 6;
  float s = 0.f;
#pragma unroll
  for (int k = 0; k < 4; ++k) {
    const int t = tid + k * 256;
    s += op_w[(long long)o * 1024 + t] * qkv_b[2048 + t];
  }
#pragma unroll
  for (int off = 32; off > 0; off >>= 1) s += __shfl_xor(s, off);
  if (lane == 0) red[wid] = s;
  __syncthreads();
  if (tid == 0) beff[1024 + o] = red[0] + red[1] + red[2] + red[3];
}

__global__ void tables_kernel(float* __restrict__ cost, float* __restrict__ sint,
                              float* __restrict__ lcos, float* __restrict__ lsin,
                              const float* __restrict__ exc) {
  const int i = blockIdx.x * blockDim.x + threadIdx.x;
  const double step = 6.283185307179586 / 1023.0;
  if (i < 1024) {
    const float a = (float)((double)i * step);
    cost[i] = cosf(a);
    sint[i] = sinf(a);
  }
  if (i < 512) {
    const float el = ((float)i / 511.0f) * TWO_PI_F;
    const float m = fmodf(el, TWO_PI_F);
    int li = (int)((m / TWO_PI_F) * 1024.0f);
    li = min(max(li, 0), 1023);
    const float a = (float)((double)li * step);
    lcos[i] = cosf(a) * exc[0];
    lsin[i] = sinf(a) * exc[0];
  }
}

extern "C" void kernel_launch(void* const* d_in, const int* in_sizes, int n_in, void* d_out,
                              int out_size, void* d_ws, size_t ws_size, hipStream_t stream) {
  const float* x = (const float*)d_in[0];
  const float* ft_w = (const float*)d_in[1];
  const float* ft_b = (const float*)d_in[2];
  const float* ln_g = (const float*)d_in[3];
  const float* ln_b = (const float*)d_in[4];
  const float* exc = (const float*)d_in[5];
  const float* qkv_w = (const float*)d_in[6];
  const float* qkv_b = (const float*)d_in[7];
  const float* op_w = (const float*)d_in[8];
  const float* op_b = (const float*)d_in[9];

  char* ws = (char*)d_ws;
  const size_t MB = 1024ull * 1024ull;
  bf16* ftw_b = (bf16*)(ws + 0);                // 1 MB
  bf16* weff = (bf16*)(ws + 1 * MB);            // 4 MB (q,k rows 0:1024; W_v2 1024:2048)
  bf16* opw_b = (bf16*)(ws + 5 * MB);           // 2 MB
  bf16* wvT = (bf16*)(ws + 7 * MB);             // 2 MB
  float* beff = (float*)(ws + 9 * MB);          // 8 KB
  float* cost = (float*)(ws + 9 * MB + 8192);
  float* sint = (float*)(ws + 9 * MB + 12288);
  float* lcos = (float*)(ws + 9 * MB + 16384);
  float* lsin = (float*)(ws + 9 * MB + 18432);
  bf16* v2T = (bf16*)(ws + 10 * MB);            // 32 MB (4 x 1024 x 4096)
  bf16* qk = (bf16*)(ws + 42 * MB);             // 32 MB (16384 x [q|k])
  bf16* x_b = (bf16*)(ws + 74 * MB);            // 16 MB, dead after stage A
  bf16* gbuf = (bf16*)(ws + 90 * MB);           // 32 MB, dead after LN
  bf16* ubuf = (bf16*)(ws + 122 * MB);          // 32 MB, dead after qk/v2 GEMMs
  bf16* sc = (bf16*)(ws + 74 * MB);             // 64 MB scores (reuses x_b/gbuf/ubuf)

  cast4_f2b<<<512, 256, 0, stream>>>(ft_w, ftw_b, 131072);
  cast4_f2b<<<1024, 256, 0, stream>>>(op_w, opw_b, 262144);
  cast4_f2b<<<2048, 256, 0, stream>>>(x, x_b, 2097152);
  fold_qkv<<<4096, 256, 0, stream>>>(qkv_w, qkv_b, weff, beff);
  fold_v_t<<<dim3(32, 32), 256, 0, stream>>>(qkv_w, wvT);
  bias_fold2<<<1024, 256, 0, stream>>>(op_w, qkv_b, beff);
  tables_kernel<<<4, 256, 0, stream>>>(cost, sint, lcos, lsin, exc);

  // W_v2 = op_w @ W_v -> weff rows 1024:2048
  gemm128<0, 1><<<dim3(8, 8), 256, 0, stream>>>(opw_b, wvT, weff + 1024 * 1024, nullptr,
                                                nullptr, 1024, 1024, 1024, 1024, 1.0f, 0, 0, 0);
  // stage A: g = gelu(x @ ft_w^T + ft_b)
  gemm128<1, 1><<<dim3(8, 128), 256, 0, stream>>>(x_b, ftw_b, gbuf, nullptr, ft_b, 512, 512,
                                                  512, 1024, 1.0f, 0, 0, 0);
  // LN + phase -> u
  ln_phase_kernel<<<16384, 256, 0, stream>>>(gbuf, ubuf, ln_g, ln_b, lcos, lsin, cost, sint);
  // qk = u @ weff[0:1024]^T + beff  (packed bf16 stores)
  gemm128<0, 1><<<dim3(8, 128), 256, 0, stream>>>(ubuf, weff, qk, nullptr, beff, 1024, 1024,
                                                  1024, 1024, 1.0f, 0, 0, 0);
  // v2T = (u @ weff[1024:2048]^T + beff2) stored transposed per batch
  gemm128<4, 0><<<dim3(8, 128), 256, 0, stream>>>(ubuf, weff + 1024 * 1024, nullptr, v2T,
                                                  beff + 1024, 1024, 1024, 1024, 0, 1.0f, 0,
                                                  0, 0);

  float* out0 = (float*)d_out;
  float* out1 = out0 + 8388608LL;
  for (int p = 0; p < 2; ++p) {
    const bf16* qbase = qk + (long long)(2 * p) * 4096 * 1024;
    // S = (q k^T) * D^-0.5, batches 2p, 2p+1
    gemm128<2, 1><<<dim3(32, 32, 2), 256, 0, stream>>>(
        qbase, qbase + 512, sc, nullptr, nullptr, 512, 1024, 1024, 4096,
        0.04419417382415922f, 4096LL * 1024, 4096LL * 1024, 4096LL * 4096);
    softmax_kernel<<<8192, 256, 0, stream>>>(sc);
    // out = P @ V2 + op_b, full K=4096, fp32 split directly into d_out
    gemm128<3, 1><<<dim3(8, 32, 2), 256, 0, stream>>>(
        sc, v2T + (long long)(2 * p) * 1024 * 4096, out0, out1, op_b, 4096, 4096, 4096, 0,
        1.0f, 4096LL * 4096, 1024LL * 4096, (long long)(2 * p) * 4096);
  }
  (void)in_sizes;
  (void)n_in;
  (void)out_size;
  (void)ws_size;
}